// Round 7
// baseline (116.177 us; speedup 1.0000x reference)
//
#include <hip/hip_runtime.h>
#include <hip/hip_bf16.h>

typedef __hip_bfloat16 bf16;
typedef __attribute__((ext_vector_type(8))) short short8;   // 8 bf16 in 4 VGPRs
typedef __attribute__((ext_vector_type(4))) float f32x4;

#define ED 768
#define NB 8
#define BS 96
#define NH 12
#define HD 64
#define SEQ 2048
#define NBATCH 4
#define NROWS (NBATCH*SEQ)   // 8192

__device__ __forceinline__ float b2f(bf16 v){ return __bfloat162float(v); }
__device__ __forceinline__ bf16 f2b(float v){ return __float2bfloat16(v); }
__device__ __forceinline__ short f2bs(float v){
    return (short)__builtin_bit_cast(unsigned short, __float2bfloat16(v));
}
__device__ __forceinline__ unsigned pkbf16(float lo, float hi){
    return (unsigned)(unsigned short)f2bs(lo) |
           ((unsigned)(unsigned short)f2bs(hi) << 16);
}

// ---------------------------------------------------------------------------
// One-time convert x (f32) -> bf16.
// ---------------------------------------------------------------------------
__global__ __launch_bounds__(256) void xcvt(
    const float* __restrict__ x, bf16* __restrict__ xb)
{
    const int idx = blockIdx.x*256 + threadIdx.x;     // one short8 per thread
    const float4 a = ((const float4*)x)[(size_t)idx*2];
    const float4 c = ((const float4*)x)[(size_t)idx*2 + 1];
    short8 o;
    o[0]=f2bs(a.x); o[1]=f2bs(a.y); o[2]=f2bs(a.z); o[3]=f2bs(a.w);
    o[4]=f2bs(c.x); o[5]=f2bs(c.y); o[6]=f2bs(c.z); o[7]=f2bs(c.w);
    ((short8*)xb)[idx] = o;
}

// ---------------------------------------------------------------------------
// Densify all 4 urdhva weight sets into Wd[z][t][s] (768x768 bf16 transposed).
// ---------------------------------------------------------------------------
__global__ __launch_bounds__(256) void densify4(
    const float* __restrict__ qWv, const float* __restrict__ qWr, const float* __restrict__ qWl,
    const float* __restrict__ kWv, const float* __restrict__ kWr, const float* __restrict__ kWl,
    const float* __restrict__ vWv, const float* __restrict__ vWr, const float* __restrict__ vWl,
    const float* __restrict__ oWv, const float* __restrict__ oWr, const float* __restrict__ oWl,
    bf16* __restrict__ WdBase)
{
    const int z = blockIdx.y;
    const float* Wv = (z==0)?qWv:(z==1)?kWv:(z==2)?vWv:oWv;
    const float* Wr = (z==0)?qWr:(z==1)?kWr:(z==2)?vWr:oWr;
    const float* Wl = (z==0)?qWl:(z==1)?kWl:(z==2)?vWl:oWl;
    bf16* Wd = WdBase + (size_t)z*ED*ED;

    const int idx = blockIdx.x*256 + threadIdx.x;   // over 768*768
    const int t = idx / ED, s = idx - t*ED;
    const int bt = t / BS, tt = t - bt*BS;
    const int bs = s / BS, ss = s - bs*BS;
    float val = 0.f;
    if (bs == bt)        val = Wv[(bt*BS + ss)*BS + tt];
    else if (bs == bt-1) val = Wr[((bt-1)*BS + ss)*BS + tt];
    else if (bs == bt+1) val = Wl[(bt*BS + ss)*BS + tt];
    Wd[idx] = f2b(val);
}

// ---------------------------------------------------------------------------
// Fully-unrolled banded K-loop body: NSTEP compile-time so the scheduler can
// software-pipeline the loads above the previous step's MFMAs (needs the
// 256-VGPR budget from __launch_bounds__(256,2); at 128 VGPR it serializes).
// ---------------------------------------------------------------------------
template<int RF, int NSTEP>
__device__ __forceinline__ void gemm_ksteps(
    const bf16* __restrict__ abase, const bf16* __restrict__ wbase,
    int klo, f32x4 acc[RF][6])
{
    #pragma unroll
    for (int s = 0; s < NSTEP; ++s) {
        const int k0 = klo + s*32;
        short8 a[RF], b[6];
        #pragma unroll
        for (int rf = 0; rf < RF; ++rf)
            a[rf] = *(const short8*)(abase + (size_t)rf*16*ED + k0);
        #pragma unroll
        for (int nf = 0; nf < 6; ++nf)
            b[nf] = *(const short8*)(wbase + (size_t)nf*16*ED + k0);
        #pragma unroll
        for (int rf = 0; rf < RF; ++rf)
            #pragma unroll
            for (int nf = 0; nf < 6; ++nf)
                acc[rf][nf] = __builtin_amdgcn_mfma_f32_16x16x32_bf16(
                                  a[rf], b[nf], acc[rf][nf], 0, 0, 0);
    }
}

// ---------------------------------------------------------------------------
// Banded MFMA GEMM. z==2 (the v projection, OBF16 path) writes its output
// TRANSPOSED: vT[col][row], packing the 4 consecutive per-reg rows into one
// 8B store. Grid: (NROWS/(RF*64), NB, Z). Block 256 = 4 waves.
// ---------------------------------------------------------------------------
template<int RF, bool OBF16>
__global__ __launch_bounds__(256, 2) void urdhva_gemm(
    const bf16* __restrict__ A,         // [NROWS][ED] bf16
    const bf16* __restrict__ WdBase,    // z-strided ED*ED
    const float* __restrict__ bias0, const float* __restrict__ bias1,
    const float* __restrict__ bias2,
    void* __restrict__ OutBase)         // z-strided NROWS*ED
{
    const int z = blockIdx.z;
    const bf16* Wd = WdBase + (size_t)z*ED*ED;
    const float* bias = (z==0) ? bias0 : (z==1) ? bias1 : bias2;

    const int lane = threadIdx.x & 63;
    const int wave = threadIdx.x >> 6;
    const int rowbase = blockIdx.x*(RF*64) + wave*(RF*16);
    const int ob = blockIdx.y;
    const int colbase = ob*BS;
    const int klo = (ob==0)    ? 0  : (ob-1)*BS;
    const int khi = (ob==NB-1) ? ED : (ob+2)*BS;

    const int l15 = lane & 15;
    const int lk8 = (lane >> 4) << 3;

    f32x4 acc[RF][6];
    #pragma unroll
    for (int i=0;i<RF;++i)
        #pragma unroll
        for (int j=0;j<6;++j) acc[i][j] = (f32x4){0.f,0.f,0.f,0.f};

    const bf16* abase = A  + (size_t)(rowbase + l15)*ED + lk8;
    const bf16* wbase = Wd + (size_t)(colbase + l15)*ED + lk8;

    if (khi - klo == 192) gemm_ksteps<RF, 6>(abase, wbase, klo, acc);
    else                  gemm_ksteps<RF, 9>(abase, wbase, klo, acc);

    const int rbase = (lane >> 4) * 4;
    if (OBF16 && z == 2) {
        // transposed store: vT[col][row], 4 rows packed per 8B
        bf16* vT = (bf16*)OutBase + (size_t)2*NROWS*ED;
        #pragma unroll
        for (int rf = 0; rf < RF; ++rf) {
            #pragma unroll
            for (int nf = 0; nf < 6; ++nf) {
                const int col = colbase + nf*16 + l15;
                const float bv = bias[col];
                const int row0 = rowbase + rf*16 + rbase;
                uint2 dw;
                dw.x = pkbf16(acc[rf][nf][0] + bv, acc[rf][nf][1] + bv);
                dw.y = pkbf16(acc[rf][nf][2] + bv, acc[rf][nf][3] + bv);
                *(uint2*)(vT + (size_t)col*NROWS + row0) = dw;
            }
        }
    } else {
        #pragma unroll
        for (int rf = 0; rf < RF; ++rf) {
            #pragma unroll
            for (int nf = 0; nf < 6; ++nf) {
                const int col = colbase + nf*16 + l15;
                const float bv = bias[col];
                #pragma unroll
                for (int r = 0; r < 4; ++r) {
                    const int row = rowbase + rf*16 + rbase + r;
                    const float vv = acc[rf][nf][r] + bv;
                    if (OBF16)
                        ((bf16*)OutBase)[(size_t)z*NROWS*ED + (size_t)row*ED + col] = f2b(vv);
                    else
                        ((float*)OutBase)[(size_t)row*ED + col] = vv;
                }
            }
        }
    }
}

// ---------------------------------------------------------------------------
// MFMA sparse attention (validated round 6). One wave = 16 queries; 8 aligned
// 16-key tiles; structural mask; softmax 2 shfl levels; PV via vT + LDS P.
// ---------------------------------------------------------------------------
__global__ __launch_bounds__(256) void sparse_attn_mfma(
    const bf16* __restrict__ q, const bf16* __restrict__ k,
    const bf16* __restrict__ vT, bf16* __restrict__ out)
{
    __shared__ __align__(16) unsigned short Plds[4][16][136];

    const int lane = threadIdx.x & 63;
    const int wid  = threadIdx.x >> 6;
    const int w  = blockIdx.x*4 + wid;        // 0 .. 6143
    const int qt = w & 127;
    const int hb = w >> 7;                    // 0..47
    const int h  = hb % NH;
    const int bb = hb / NH;
    const int i0 = qt << 4;

    const int l15 = lane & 15;
    const int g   = lane >> 4;

    const bf16* qbase = q + ((size_t)bb*SEQ + i0 + l15)*ED + h*HD + g*8;
    const short8 qf0 = *(const short8*)qbase;
    const short8 qf1 = *(const short8*)(qbase + 32);

    int bases[8];
    bases[0]=i0;     bases[1]=i0-16;  bases[2]=i0-32;  bases[3]=i0-64;
    bases[4]=i0-128; bases[5]=i0-256; bases[6]=i0-512; bases[7]=i0-1024;

    const bf16* kbb = k + (size_t)bb*SEQ*ED + h*HD;

    float p[8][4];
    #pragma unroll
    for (int t = 0; t < 8; ++t) {
        f32x4 acc = (f32x4){0.f,0.f,0.f,0.f};
        if (bases[t] >= 0) {
            const bf16* kp = kbb + (size_t)(bases[t] + l15)*ED + g*8;
            const short8 kf0 = *(const short8*)kp;
            const short8 kf1 = *(const short8*)(kp + 32);
            acc = __builtin_amdgcn_mfma_f32_16x16x32_bf16(kf0, qf0, acc, 0,0,0);
            acc = __builtin_amdgcn_mfma_f32_16x16x32_bf16(kf1, qf1, acc, 0,0,0);
        }
        const int Dt = i0 - bases[t];
        #pragma unroll
        for (int r = 0; r < 4; ++r) {
            const int delta = Dt + l15 - 4*g - r;
            const bool val = (bases[t] >= 0) &&
                (((unsigned)delta <= 4u) ||
                 (delta >= 8 && (delta & (delta-1)) == 0));
            p[t][r] = val ? acc[r]*0.125f : -1e30f;   // 1/sqrt(64)
        }
    }

    float m = -1e30f;
    #pragma unroll
    for (int t = 0; t < 8; ++t)
        #pragma unroll
        for (int r = 0; r < 4; ++r) m = fmaxf(m, p[t][r]);
    m = fmaxf(m, __shfl_xor(m, 16));
    m = fmaxf(m, __shfl_xor(m, 32));

    float den = 0.f;
    #pragma unroll
    for (int t = 0; t < 8; ++t)
        #pragma unroll
        for (int r = 0; r < 4; ++r) { p[t][r] = __expf(p[t][r] - m); den += p[t][r]; }
    den += __shfl_xor(den, 16);
    den += __shfl_xor(den, 32);
    const float inv = 1.f / den;

    {
        char* prow = (char*)&Plds[wid][l15][0];
        #pragma unroll
        for (int t = 0; t < 8; ++t) {
            *(unsigned*)(prow + 32*t + 8*g)     = pkbf16(p[t][0]*inv, p[t][1]*inv);
            *(unsigned*)(prow + 32*t + 8*g + 4) = pkbf16(p[t][2]*inv, p[t][3]*inv);
        }
    }

    f32x4 accO[4];
    #pragma unroll
    for (int nt = 0; nt < 4; ++nt) accO[nt] = (f32x4){0.f,0.f,0.f,0.f};

    const bf16* vbb = vT + (size_t)bb*SEQ;
    #pragma unroll
    for (int u = 0; u < 4; ++u) {
        if (bases[2*u] < 0 && bases[2*u+1] < 0) continue;
        const short8 pa = *(const short8*)((char*)&Plds[wid][l15][0] + 64*u + 16*g);
        const int tb  = (g & 2) ? bases[2*u+1] : bases[2*u];
        const int tbc = (tb < 0 ? 0 : tb) + 8*(g & 1);
        #pragma unroll
        for (int nt = 0; nt < 4; ++nt) {
            const short8 vb = *(const short8*)(vbb +
                (size_t)(h*HD + 16*nt + l15)*NROWS + tbc);
            accO[nt] = __builtin_amdgcn_mfma_f32_16x16x32_bf16(pa, vb, accO[nt], 0,0,0);
        }
    }

    #pragma unroll
    for (int nt = 0; nt < 4; ++nt)
        #pragma unroll
        for (int r = 0; r < 4; ++r)
            out[((size_t)bb*SEQ + i0 + 4*g + r)*ED + h*HD + 16*nt + l15] =
                f2b(accO[nt][r]);
}

// ---------------------------------------------------------------------------
extern "C" void kernel_launch(void* const* d_in, const int* in_sizes, int n_in,
                              void* d_out, int out_size, void* d_ws, size_t ws_size,
                              hipStream_t stream) {
    const float* x   = (const float*)d_in[0];
    const float* qWv = (const float*)d_in[1];
    const float* qWr = (const float*)d_in[2];
    const float* qWl = (const float*)d_in[3];
    const float* qb  = (const float*)d_in[4];
    const float* kWv = (const float*)d_in[5];
    const float* kWr = (const float*)d_in[6];
    const float* kWl = (const float*)d_in[7];
    const float* kb  = (const float*)d_in[8];
    const float* vWv = (const float*)d_in[9];
    const float* vWr = (const float*)d_in[10];
    const float* vWl = (const float*)d_in[11];
    const float* vb  = (const float*)d_in[12];
    const float* oWv = (const float*)d_in[13];
    const float* oWr = (const float*)d_in[14];
    const float* oWl = (const float*)d_in[15];
    const float* ob  = (const float*)d_in[16];
    // d_in[17] = sparse_mask: structural, computed analytically in-kernel.

    const size_t QKV = (size_t)NROWS*ED;   // 6.29M elems
    bf16* xb  = (bf16*)d_ws;
    bf16* q   = xb + QKV;
    bf16* k   = q + QKV;
    bf16* vT  = k + QKV;                   // v, stored transposed [col][row]
    bf16* ao  = vT + QKV;
    bf16* Wd  = ao + QKV;                  // 4 x ED*ED (q,k,v,o)
    bf16* Wdo = Wd + (size_t)3*ED*ED;

    xcvt<<<NROWS*ED/8/256, 256, 0, stream>>>(x, xb);
    densify4<<<dim3(ED*ED/256, 4), 256, 0, stream>>>(
        qWv,qWr,qWl, kWv,kWr,kWl, vWv,vWr,vWl, oWv,oWr,oWl, Wd);

    // fused q/k/v banded GEMM; z==2 writes vT transposed
    urdhva_gemm<4, true><<<dim3(NROWS/256, NB, 3), 256, 0, stream>>>(
        xb, Wd, qb, kb, vb, q);

    sparse_attn_mfma<<<(NBATCH*NH*(SEQ/16))/4, 256, 0, stream>>>(q, k, vT, ao);

    urdhva_gemm<4, false><<<dim3(NROWS/256, NB, 1), 256, 0, stream>>>(
        ao, Wdo, ob, ob, ob, d_out);
}

// Round 8
// 87.242 us; speedup vs baseline: 1.3317x; 1.3317x over previous
//
#include <hip/hip_runtime.h>
#include <hip/hip_bf16.h>

typedef __hip_bfloat16 bf16;
typedef __attribute__((ext_vector_type(8))) short short8;   // 8 bf16 in 4 VGPRs
typedef __attribute__((ext_vector_type(4))) float f32x4;

#define ED 768
#define NB 8
#define BS 96
#define NH 12
#define HD 64
#define SEQ 2048
#define NBATCH 4
#define NROWS (NBATCH*SEQ)   // 8192

__device__ __forceinline__ float b2f(bf16 v){ return __bfloat162float(v); }
__device__ __forceinline__ bf16 f2b(float v){ return __float2bfloat16(v); }
__device__ __forceinline__ short f2bs(float v){
    return (short)__builtin_bit_cast(unsigned short, __float2bfloat16(v));
}
__device__ __forceinline__ unsigned pkbf16(float lo, float hi){
    return (unsigned)(unsigned short)f2bs(lo) |
           ((unsigned)(unsigned short)f2bs(hi) << 16);
}
__device__ __forceinline__ void gload_lds16(const void* g, void* l) {
    __builtin_amdgcn_global_load_lds(
        (const __attribute__((address_space(1))) unsigned*)g,
        (__attribute__((address_space(3))) unsigned*)l, 16, 0, 0);
}

// ---------------------------------------------------------------------------
// One-time convert x (f32) -> bf16.
// ---------------------------------------------------------------------------
__global__ __launch_bounds__(256) void xcvt(
    const float* __restrict__ x, bf16* __restrict__ xb)
{
    const int idx = blockIdx.x*256 + threadIdx.x;     // one short8 per thread
    const float4 a = ((const float4*)x)[(size_t)idx*2];
    const float4 c = ((const float4*)x)[(size_t)idx*2 + 1];
    short8 o;
    o[0]=f2bs(a.x); o[1]=f2bs(a.y); o[2]=f2bs(a.z); o[3]=f2bs(a.w);
    o[4]=f2bs(c.x); o[5]=f2bs(c.y); o[6]=f2bs(c.z); o[7]=f2bs(c.w);
    ((short8*)xb)[idx] = o;
}

// ---------------------------------------------------------------------------
// Densify all 4 urdhva weight sets into Wd[z][t][s] (768x768 bf16 transposed).
// ---------------------------------------------------------------------------
__global__ __launch_bounds__(256) void densify4(
    const float* __restrict__ qWv, const float* __restrict__ qWr, const float* __restrict__ qWl,
    const float* __restrict__ kWv, const float* __restrict__ kWr, const float* __restrict__ kWl,
    const float* __restrict__ vWv, const float* __restrict__ vWr, const float* __restrict__ vWl,
    const float* __restrict__ oWv, const float* __restrict__ oWr, const float* __restrict__ oWl,
    bf16* __restrict__ WdBase)
{
    const int z = blockIdx.y;
    const float* Wv = (z==0)?qWv:(z==1)?kWv:(z==2)?vWv:oWv;
    const float* Wr = (z==0)?qWr:(z==1)?kWr:(z==2)?vWr:oWr;
    const float* Wl = (z==0)?qWl:(z==1)?kWl:(z==2)?vWl:oWl;
    bf16* Wd = WdBase + (size_t)z*ED*ED;

    const int idx = blockIdx.x*256 + threadIdx.x;   // over 768*768
    const int t = idx / ED, s = idx - t*ED;
    const int bt = t / BS, tt = t - bt*BS;
    const int bs = s / BS, ss = s - bs*BS;
    float val = 0.f;
    if (bs == bt)        val = Wv[(bt*BS + ss)*BS + tt];
    else if (bs == bt-1) val = Wr[((bt-1)*BS + ss)*BS + tt];
    else if (bs == bt+1) val = Wl[(bt*BS + ss)*BS + tt];
    Wd[idx] = f2b(val);
}

// ---------------------------------------------------------------------------
// LDS-staged banded GEMM, T3 minimum 2-phase pipeline.
// Tile: BM=128 rows x BN=96 cols x BK=32. 4 waves; wave = 32 rows x 96 cols.
// Stage via global_load_lds(16B): A-tile 8KB + B-tile 6KB = 14 x 1KB chunks.
// LDS layout [row][32k] linear (gload_lds needs linear dest); bank-conflict
// fix per rule #21: pre-swizzle the GLOBAL source k-slot with
// slot' = slot ^ ((r ^ (r>>2)) & 3), apply the same XOR on ds_read. -> 2-way
// max (free, m136).
// ---------------------------------------------------------------------------
__device__ __forceinline__ void stage_tile(
    const bf16* __restrict__ Ag, const bf16* __restrict__ Wd,
    int rowbase, int colbase, int k0,
    bf16* As, bf16* Bs, int wave, int lane)
{
    const int sub  = lane >> 2;                       // row-within-16-chunk
    const int slot = lane & 3;                        // 16B slot in 64B row
    const int sws  = ((lane >> 2) ^ (lane >> 4)) & 3; // = sw(row), lane-only
    const int kofs = ((slot ^ sws) << 3);             // element offset
    #pragma unroll
    for (int c = wave; c < 14; c += 4) {
        if (c < 8) {
            const int r = c*16 + sub;
            gload_lds16(Ag + (size_t)(rowbase + r)*ED + k0 + kofs,
                        (char*)As + c*1024);
        } else {
            const int col = (c-8)*16 + sub;
            gload_lds16(Wd + (size_t)(colbase + col)*ED + k0 + kofs,
                        (char*)Bs + (c-8)*1024);
        }
    }
}

__device__ __forceinline__ void compute_tile(
    const bf16* As, const bf16* Bs, int wave, int lane, f32x4 acc[2][6])
{
    const int l15 = lane & 15;
    const int s   = lane >> 4;
    const int swr = (l15 ^ (l15 >> 2)) & 3;
    const int rsel = ((s ^ swr) << 4);                // byte slot in 64B row

    short8 a[2], b[6];
    #pragma unroll
    for (int rf = 0; rf < 2; ++rf)
        a[rf] = *(const short8*)((const char*)As +
                    (wave*32 + rf*16 + l15)*64 + rsel);
    #pragma unroll
    for (int nf = 0; nf < 6; ++nf)
        b[nf] = *(const short8*)((const char*)Bs + (nf*16 + l15)*64 + rsel);
    #pragma unroll
    for (int rf = 0; rf < 2; ++rf)
        #pragma unroll
        for (int nf = 0; nf < 6; ++nf)
            acc[rf][nf] = __builtin_amdgcn_mfma_f32_16x16x32_bf16(
                              a[rf], b[nf], acc[rf][nf], 0, 0, 0);
}

template<bool OBF16>
__global__ __launch_bounds__(256, 2) void urdhva_gemm_lds(
    const bf16* __restrict__ A,         // [NROWS][ED] bf16
    const bf16* __restrict__ WdBase,    // z-strided ED*ED
    const float* __restrict__ bias0, const float* __restrict__ bias1,
    const float* __restrict__ bias2,
    void* __restrict__ OutBase)         // z-strided NROWS*ED
{
    __shared__ __align__(16) bf16 As[2][128*32];
    __shared__ __align__(16) bf16 Bs[2][96*32];

    const int z = blockIdx.z;
    const bf16* Wd = WdBase + (size_t)z*ED*ED;
    const float* bias = (z==0) ? bias0 : (z==1) ? bias1 : bias2;

    const int lane = threadIdx.x & 63;
    const int wave = threadIdx.x >> 6;
    const int rowbase = blockIdx.x*128;
    const int ob = blockIdx.y;
    const int colbase = ob*BS;
    const int klo = (ob==0)    ? 0  : (ob-1)*BS;
    const int khi = (ob==NB-1) ? ED : (ob+2)*BS;
    const int nt  = (khi - klo) >> 5;   // 6 or 9 K-tiles

    f32x4 acc[2][6];
    #pragma unroll
    for (int i=0;i<2;++i)
        #pragma unroll
        for (int j=0;j<6;++j) acc[i][j] = (f32x4){0.f,0.f,0.f,0.f};

    stage_tile(A, Wd, rowbase, colbase, klo, As[0], Bs[0], wave, lane);
    __syncthreads();                       // vmcnt(0): tile0 ready
    int cur = 0;
    for (int t = 0; t < nt-1; ++t) {
        stage_tile(A, Wd, rowbase, colbase, klo + (t+1)*32,
                   As[cur^1], Bs[cur^1], wave, lane);   // async prefetch
        compute_tile(As[cur], Bs[cur], wave, lane, acc);
        __syncthreads();                   // next tile staged + cur free
        cur ^= 1;
    }
    compute_tile(As[cur], Bs[cur], wave, lane, acc);

    const int l15 = lane & 15;
    const int rbase = (lane >> 4) * 4;
    const int wrow = rowbase + wave*32;
    if (OBF16 && z == 2) {
        // transposed store: vT[col][row], 4 rows packed per 8B
        bf16* vT = (bf16*)OutBase + (size_t)2*NROWS*ED;
        #pragma unroll
        for (int rf = 0; rf < 2; ++rf) {
            #pragma unroll
            for (int nf = 0; nf < 6; ++nf) {
                const int col = colbase + nf*16 + l15;
                const float bv = bias[col];
                const int row0 = wrow + rf*16 + rbase;
                uint2 dw;
                dw.x = pkbf16(acc[rf][nf][0] + bv, acc[rf][nf][1] + bv);
                dw.y = pkbf16(acc[rf][nf][2] + bv, acc[rf][nf][3] + bv);
                *(uint2*)(vT + (size_t)col*NROWS + row0) = dw;
            }
        }
    } else {
        #pragma unroll
        for (int rf = 0; rf < 2; ++rf) {
            #pragma unroll
            for (int nf = 0; nf < 6; ++nf) {
                const int col = colbase + nf*16 + l15;
                const float bv = bias[col];
                #pragma unroll
                for (int r = 0; r < 4; ++r) {
                    const int row = wrow + rf*16 + rbase + r;
                    const float vv = acc[rf][nf][r] + bv;
                    if (OBF16)
                        ((bf16*)OutBase)[(size_t)z*NROWS*ED + (size_t)row*ED + col] = f2b(vv);
                    else
                        ((float*)OutBase)[(size_t)row*ED + col] = vv;
                }
            }
        }
    }
}

// ---------------------------------------------------------------------------
// MFMA sparse attention (validated round 6). One wave = 16 queries; 8 aligned
// 16-key tiles; structural mask; softmax 2 shfl levels; PV via vT + LDS P.
// ---------------------------------------------------------------------------
__global__ __launch_bounds__(256) void sparse_attn_mfma(
    const bf16* __restrict__ q, const bf16* __restrict__ k,
    const bf16* __restrict__ vT, bf16* __restrict__ out)
{
    __shared__ __align__(16) unsigned short Plds[4][16][136];

    const int lane = threadIdx.x & 63;
    const int wid  = threadIdx.x >> 6;
    const int w  = blockIdx.x*4 + wid;        // 0 .. 6143
    const int qt = w & 127;
    const int hb = w >> 7;                    // 0..47
    const int h  = hb % NH;
    const int bb = hb / NH;
    const int i0 = qt << 4;

    const int l15 = lane & 15;
    const int g   = lane >> 4;

    const bf16* qbase = q + ((size_t)bb*SEQ + i0 + l15)*ED + h*HD + g*8;
    const short8 qf0 = *(const short8*)qbase;
    const short8 qf1 = *(const short8*)(qbase + 32);

    int bases[8];
    bases[0]=i0;     bases[1]=i0-16;  bases[2]=i0-32;  bases[3]=i0-64;
    bases[4]=i0-128; bases[5]=i0-256; bases[6]=i0-512; bases[7]=i0-1024;

    const bf16* kbb = k + (size_t)bb*SEQ*ED + h*HD;

    float p[8][4];
    #pragma unroll
    for (int t = 0; t < 8; ++t) {
        f32x4 acc = (f32x4){0.f,0.f,0.f,0.f};
        if (bases[t] >= 0) {
            const bf16* kp = kbb + (size_t)(bases[t] + l15)*ED + g*8;
            const short8 kf0 = *(const short8*)kp;
            const short8 kf1 = *(const short8*)(kp + 32);
            acc = __builtin_amdgcn_mfma_f32_16x16x32_bf16(kf0, qf0, acc, 0,0,0);
            acc = __builtin_amdgcn_mfma_f32_16x16x32_bf16(kf1, qf1, acc, 0,0,0);
        }
        const int Dt = i0 - bases[t];
        #pragma unroll
        for (int r = 0; r < 4; ++r) {
            const int delta = Dt + l15 - 4*g - r;
            const bool val = (bases[t] >= 0) &&
                (((unsigned)delta <= 4u) ||
                 (delta >= 8 && (delta & (delta-1)) == 0));
            p[t][r] = val ? acc[r]*0.125f : -1e30f;   // 1/sqrt(64)
        }
    }

    float m = -1e30f;
    #pragma unroll
    for (int t = 0; t < 8; ++t)
        #pragma unroll
        for (int r = 0; r < 4; ++r) m = fmaxf(m, p[t][r]);
    m = fmaxf(m, __shfl_xor(m, 16));
    m = fmaxf(m, __shfl_xor(m, 32));

    float den = 0.f;
    #pragma unroll
    for (int t = 0; t < 8; ++t)
        #pragma unroll
        for (int r = 0; r < 4; ++r) { p[t][r] = __expf(p[t][r] - m); den += p[t][r]; }
    den += __shfl_xor(den, 16);
    den += __shfl_xor(den, 32);
    const float inv = 1.f / den;

    {
        char* prow = (char*)&Plds[wid][l15][0];
        #pragma unroll
        for (int t = 0; t < 8; ++t) {
            *(unsigned*)(prow + 32*t + 8*g)     = pkbf16(p[t][0]*inv, p[t][1]*inv);
            *(unsigned*)(prow + 32*t + 8*g + 4) = pkbf16(p[t][2]*inv, p[t][3]*inv);
        }
    }

    f32x4 accO[4];
    #pragma unroll
    for (int nt = 0; nt < 4; ++nt) accO[nt] = (f32x4){0.f,0.f,0.f,0.f};

    const bf16* vbb = vT + (size_t)bb*SEQ;
    #pragma unroll
    for (int u = 0; u < 4; ++u) {
        if (bases[2*u] < 0 && bases[2*u+1] < 0) continue;
        const short8 pa = *(const short8*)((char*)&Plds[wid][l15][0] + 64*u + 16*g);
        const int tb  = (g & 2) ? bases[2*u+1] : bases[2*u];
        const int tbc = (tb < 0 ? 0 : tb) + 8*(g & 1);
        #pragma unroll
        for (int nt = 0; nt < 4; ++nt) {
            const short8 vb = *(const short8*)(vbb +
                (size_t)(h*HD + 16*nt + l15)*NROWS + tbc);
            accO[nt] = __builtin_amdgcn_mfma_f32_16x16x32_bf16(pa, vb, accO[nt], 0,0,0);
        }
    }

    #pragma unroll
    for (int nt = 0; nt < 4; ++nt)
        #pragma unroll
        for (int r = 0; r < 4; ++r)
            out[((size_t)bb*SEQ + i0 + 4*g + r)*ED + h*HD + 16*nt + l15] =
                f2b(accO[nt][r]);
}

// ---------------------------------------------------------------------------
extern "C" void kernel_launch(void* const* d_in, const int* in_sizes, int n_in,
                              void* d_out, int out_size, void* d_ws, size_t ws_size,
                              hipStream_t stream) {
    const float* x   = (const float*)d_in[0];
    const float* qWv = (const float*)d_in[1];
    const float* qWr = (const float*)d_in[2];
    const float* qWl = (const float*)d_in[3];
    const float* qb  = (const float*)d_in[4];
    const float* kWv = (const float*)d_in[5];
    const float* kWr = (const float*)d_in[6];
    const float* kWl = (const float*)d_in[7];
    const float* kb  = (const float*)d_in[8];
    const float* vWv = (const float*)d_in[9];
    const float* vWr = (const float*)d_in[10];
    const float* vWl = (const float*)d_in[11];
    const float* vb  = (const float*)d_in[12];
    const float* oWv = (const float*)d_in[13];
    const float* oWr = (const float*)d_in[14];
    const float* oWl = (const float*)d_in[15];
    const float* ob  = (const float*)d_in[16];
    // d_in[17] = sparse_mask: structural, computed analytically in-kernel.

    const size_t QKV = (size_t)NROWS*ED;   // 6.29M elems
    bf16* xb  = (bf16*)d_ws;
    bf16* q   = xb + QKV;
    bf16* k   = q + QKV;
    bf16* vT  = k + QKV;                   // v, stored transposed [col][row]
    bf16* ao  = vT + QKV;
    bf16* Wd  = ao + QKV;                  // 4 x ED*ED (q,k,v,o)
    bf16* Wdo = Wd + (size_t)3*ED*ED;

    xcvt<<<NROWS*ED/8/256, 256, 0, stream>>>(x, xb);
    densify4<<<dim3(ED*ED/256, 4), 256, 0, stream>>>(
        qWv,qWr,qWl, kWv,kWr,kWl, vWv,vWr,vWl, oWv,oWr,oWl, Wd);

    // fused q/k/v banded GEMM; z==2 writes vT transposed
    urdhva_gemm_lds<true><<<dim3(NROWS/128, NB, 3), 256, 0, stream>>>(
        xb, Wd, qb, kb, vb, q);

    sparse_attn_mfma<<<(NBATCH*NH*(SEQ/16))/4, 256, 0, stream>>>(q, k, vT, ao);

    urdhva_gemm_lds<false><<<dim3(NROWS/128, NB, 1), 256, 0, stream>>>(
        ao, Wdo, ob, ob, ob, d_out);
}